// Round 6
// baseline (310.725 us; speedup 1.0000x reference)
//
#include <hip/hip_runtime.h>
#include <hip/hip_bf16.h>

// MultiHeadAttention: B=4, T=2048, DIM=64, H=12. fp32 I/O.
// Flat-reshape semantics: QKV are (8192,768) row-major; attention "slices" are
// contiguous 131072-element chunks (NOT token-aligned). Roles: queries = K rows
// (i), keys = Q rows (j), values = V rows, softmax over j.
// Round 6: attn = zero-barrier 1-wave blocks; Q/V fragments direct from L2;
// P packed by truncation (l accumulated from truncated values -> bias-free);
// XCD swizzle for slice L2 locality; vtrans bank-conflict fix via XOR swizzle.

#define DIM 64
#define NH 12
#define HD 768
#define BT 8192
#define TSEQ 2048
#define NSLICE 48
#define SLICE (TSEQ*DIM)

#define LDP 72   // P LDS row stride (ushorts): 16B-aligned rows, ~2-way banks
#define LDT 72   // vtrans LDS row stride

typedef unsigned short ushort;
typedef __attribute__((ext_vector_type(8))) short bf16x8;
typedef __attribute__((ext_vector_type(4))) float f32x4;

__device__ __forceinline__ float b2f(ushort u) {
    union { unsigned int i; float f; } v; v.i = ((unsigned int)u) << 16; return v.f;
}
__device__ __forceinline__ ushort f2b(float f) {
    union { float f; unsigned int i; } v; v.f = f;
    unsigned int x = v.i;
    return (ushort)((x + 0x7fffu + ((x >> 16) & 1u)) >> 16);  // RNE
}

// ---------------- prep (merged): weights transpose + x convert -------------
// blocks 0..47: W-transpose (z = bx/12, tile = bx%12); blocks 48..303: x->bf16
__global__ __launch_bounds__(256) void prep_kernel(
    const float* __restrict__ x,
    const float* __restrict__ Wq, const float* __restrict__ Wk,
    const float* __restrict__ Wv, const float* __restrict__ Wo,
    ushort* __restrict__ xb, ushort* __restrict__ Wt, ushort* __restrict__ Wot)
{
    __shared__ float tile[64][65];
    int bx = blockIdx.x;
    int t = threadIdx.x;
    if (bx >= 48) {                       // x (fp32) -> xb (bf16), 2048/block
        int idx = ((bx - 48) * 256 + t) * 8;
        float4 a = *(const float4*)&x[idx];
        float4 b = *(const float4*)&x[idx + 4];
        ushort tmp[8] __attribute__((aligned(16)));
        tmp[0]=f2b(a.x); tmp[1]=f2b(a.y); tmp[2]=f2b(a.z); tmp[3]=f2b(a.w);
        tmp[4]=f2b(b.x); tmp[5]=f2b(b.y); tmp[6]=f2b(b.z); tmp[7]=f2b(b.w);
        *(float4*)&xb[idx] = *(const float4*)tmp;
        return;
    }
    int z = bx / 12, bt = bx % 12;
    const float* __restrict__ IN = (z == 0) ? Wq : (z == 1) ? Wk : (z == 2) ? Wv : Wo;
    int inStride  = (z < 3) ? HD : DIM;
    int outStride = (z < 3) ? DIM : HD;
    int rbase = (z < 3) ? 0 : bt * 64;
    int cbase = (z < 3) ? bt * 64 : 0;
    ushort* __restrict__ OUT = (z < 3) ? (Wt + (size_t)z * HD * DIM) : Wot;
    int r = t >> 2, c0 = (t & 3) * 16;
    #pragma unroll
    for (int cc = 0; cc < 16; cc += 4) {
        float4 a = *(const float4*)&IN[(size_t)(rbase + r) * inStride + cbase + c0 + cc];
        tile[r][c0 + cc] = a.x; tile[r][c0 + cc + 1] = a.y;
        tile[r][c0 + cc + 2] = a.z; tile[r][c0 + cc + 3] = a.w;
    }
    __syncthreads();
    int cl = t >> 2, r0 = (t & 3) * 16;
    ushort tmp[16] __attribute__((aligned(16)));
    #pragma unroll
    for (int rr = 0; rr < 16; ++rr) tmp[rr] = f2b(tile[r0 + rr][cl]);
    *(float4*)&OUT[(size_t)(cbase + cl) * outStride + rbase + r0] = *(const float4*)tmp;
    *(float4*)&OUT[(size_t)(cbase + cl) * outStride + rbase + r0 + 8] = *(const float4*)&tmp[8];
}

// ---------------- Kernel 1: Q/K/V = xb @ W (MFMA, no LDS) ------------------
__global__ __launch_bounds__(256) void qkv_kernel(
    const ushort* __restrict__ xb, const ushort* __restrict__ Wt,
    ushort* __restrict__ Q, ushort* __restrict__ K, ushort* __restrict__ V)
{
    int rowbase = blockIdx.x * 64;
    int ct = blockIdx.y;
    int which = ct / 12;
    int col0 = (ct % 12) * 64;
    const ushort* __restrict__ Wz = Wt + (size_t)which * HD * DIM;  // (768x64)
    ushort* __restrict__ Y = (which == 0) ? Q : (which == 1) ? K : V;
    int t = threadIdx.x, w = t >> 6, lane = t & 63;
    int ln = lane & 15, q = lane >> 4;
    int m0 = rowbase + w * 16;

    bf16x8 af0 = *(const bf16x8*)&xb[(size_t)(m0 + ln) * DIM + q * 8];
    bf16x8 af1 = *(const bf16x8*)&xb[(size_t)(m0 + ln) * DIM + 32 + q * 8];
    #pragma unroll
    for (int nt = 0; nt < 4; ++nt) {
        int n = col0 + nt * 16 + ln;
        bf16x8 bf0 = *(const bf16x8*)&Wz[(size_t)n * DIM + q * 8];
        bf16x8 bf1 = *(const bf16x8*)&Wz[(size_t)n * DIM + 32 + q * 8];
        f32x4 acc = (f32x4){0.f, 0.f, 0.f, 0.f};
        acc = __builtin_amdgcn_mfma_f32_16x16x32_bf16(af0, bf0, acc, 0, 0, 0);
        acc = __builtin_amdgcn_mfma_f32_16x16x32_bf16(af1, bf1, acc, 0, 0, 0);
        #pragma unroll
        for (int r = 0; r < 4; ++r)
            Y[(size_t)(m0 + q * 4 + r) * HD + col0 + nt * 16 + ln] = f2b(acc[r]);
    }
}

// ---------------- Kernel 1b: Vt[s][d][t] = V[s][t][d] ----------------------
// Transposed SCALAR writes with XOR-swizzled t-group (banks spread), vector
// row reads un-swizzle. Element (d,t) lives at tileT[d*LDT + ((t>>3)^(d>>3))*8 + (t&7)].
__global__ __launch_bounds__(256) void vtrans_kernel(
    const ushort* __restrict__ V, ushort* __restrict__ Vt)
{
    __shared__ ushort tileT[64 * LDT];
    int tt = blockIdx.x, s = blockIdx.y;
    const ushort* __restrict__ Vp = V + (size_t)s * SLICE;
    ushort* __restrict__ Vo = Vt + (size_t)s * SLICE;
    int t = threadIdx.x;
    int r = t >> 3, c = (t & 7) * 8;          // r = t-row (0..31), c = d-base
    ushort va[8] __attribute__((aligned(16)));
    ushort vb[8] __attribute__((aligned(16)));
    *(float4*)va = *(const float4*)&Vp[(size_t)(tt * 64 + r) * DIM + c];
    *(float4*)vb = *(const float4*)&Vp[(size_t)(tt * 64 + r + 32) * DIM + c];
    int g0 = ((r >> 3) ^ (c >> 3)) * 8 + (r & 7);
    int g1 = (((r + 32) >> 3) ^ (c >> 3)) * 8 + (r & 7);
    #pragma unroll
    for (int k = 0; k < 8; ++k) {
        tileT[(c + k) * LDT + g0] = va[k];
        tileT[(c + k) * LDT + g1] = vb[k];
    }
    __syncthreads();
    #pragma unroll
    for (int j = 0; j < 2; ++j) {
        int flat = t + 256 * j;               // 512 float4s of the [d][t] tile
        int d = flat >> 3, tg = flat & 7;
        int sg = tg ^ ((d >> 3) & 7);
        float4 vv = *(const float4*)&tileT[d * LDT + sg * 8];
        *(float4*)&Vo[(size_t)d * TSEQ + tt * 64 + tg * 8] = vv;
    }
}

// ---------------- Kernel 2: zero-barrier MFMA flash attention --------------
// 3072 one-wave blocks (64 itiles x 48 slices), XCD-swizzled: bid = xcd + 8*
// (itile + 64*sgrp), s = sgrp*8+xcd. Wave owns 32 i-rows; Q/V frags direct
// from global (L2); P via wave-private LDS (no barriers anywhere).
__global__ __launch_bounds__(64) void attn_kernel(
    const ushort* __restrict__ Qs, const ushort* __restrict__ Ks,
    const ushort* __restrict__ Vts, ushort* __restrict__ Zs)
{
    const float SCALE2 = 0.18033688011112042f;   // 0.125 * log2(e)
    __shared__ ushort Pme[32 * LDP];
    int bid = blockIdx.x;
    int s = (bid >> 9) * 8 + (bid & 7);
    int itile = (bid >> 3) & 63;
    const ushort* __restrict__ Qp = Qs + (size_t)s * SLICE;
    const ushort* __restrict__ Kp = Ks + (size_t)s * SLICE;
    const ushort* __restrict__ Vp = Vts + (size_t)s * SLICE;   // [64][2048]
    ushort* __restrict__ Zp = Zs + (size_t)s * SLICE;
    int lane = threadIdx.x;
    int ln = lane & 15, q = lane >> 4;

    // persistent K fragments (B operand: rows i, contiguous k)
    bf16x8 kf[2][2];
    #pragma unroll
    for (int ih = 0; ih < 2; ++ih) {
        int i0 = itile * 32 + ih * 16 + ln;
        kf[ih][0] = *(const bf16x8*)&Kp[(size_t)i0 * DIM + q * 8];
        kf[ih][1] = *(const bf16x8*)&Kp[(size_t)i0 * DIM + 32 + q * 8];
    }
    f32x4 Of[2][4];
    #pragma unroll
    for (int ih = 0; ih < 2; ++ih)
        #pragma unroll
        for (int dt = 0; dt < 4; ++dt) Of[ih][dt] = (f32x4){0.f, 0.f, 0.f, 0.f};
    float lsum[2] = {0.f, 0.f};

    for (int jt = 0; jt < TSEQ; jt += 64) {
        // issue all global fragment loads up front (L2 hits; no barriers)
        bf16x8 aq[4][2];                      // Q A-frags: m=j, k
        #pragma unroll
        for (int mt = 0; mt < 4; ++mt) {
            aq[mt][0] = *(const bf16x8*)&Qp[(size_t)(jt + mt * 16 + ln) * DIM + q * 8];
            aq[mt][1] = *(const bf16x8*)&Qp[(size_t)(jt + mt * 16 + ln) * DIM + 32 + q * 8];
        }
        bf16x8 vb[4][2];                      // V B-frags: n=d, k=j
        #pragma unroll
        for (int dt = 0; dt < 4; ++dt) {
            vb[dt][0] = *(const bf16x8*)&Vp[(size_t)(dt * 16 + ln) * TSEQ + jt + q * 8];
            vb[dt][1] = *(const bf16x8*)&Vp[(size_t)(dt * 16 + ln) * TSEQ + jt + 32 + q * 8];
        }
        // S^T = Q*K^T per i-half, then softmax+truncation-pack into LDS
        #pragma unroll
        for (int ih = 0; ih < 2; ++ih) {
            f32x4 Sf[4];
            #pragma unroll
            for (int mt = 0; mt < 4; ++mt) {
                f32x4 acc = (f32x4){0.f, 0.f, 0.f, 0.f};
                acc = __builtin_amdgcn_mfma_f32_16x16x32_bf16(aq[mt][0], kf[ih][0], acc, 0, 0, 0);
                acc = __builtin_amdgcn_mfma_f32_16x16x32_bf16(aq[mt][1], kf[ih][1], acc, 0, 0, 0);
                Sf[mt] = acc;
            }
            float ls = 0.f;
            #pragma unroll
            for (int mt = 0; mt < 4; ++mt) {
                float p0 = __builtin_amdgcn_exp2f(Sf[mt][0] * SCALE2);
                float p1 = __builtin_amdgcn_exp2f(Sf[mt][1] * SCALE2);
                float p2 = __builtin_amdgcn_exp2f(Sf[mt][2] * SCALE2);
                float p3 = __builtin_amdgcn_exp2f(Sf[mt][3] * SCALE2);
                unsigned int b0 = __float_as_uint(p0), b1 = __float_as_uint(p1);
                unsigned int b2 = __float_as_uint(p2), b3 = __float_as_uint(p3);
                unsigned int t1 = b1 & 0xFFFF0000u, t3 = b3 & 0xFFFF0000u;
                unsigned int h01 = (b0 >> 16) | t1;
                unsigned int h23 = (b2 >> 16) | t3;
                // l from TRUNCATED values -> weights sum exactly to 1
                ls += __uint_as_float(h01 << 16) + __uint_as_float(t1)
                    + __uint_as_float(h23 << 16) + __uint_as_float(t3);
                *(uint2*)&Pme[(ih * 16 + ln) * LDP + mt * 16 + q * 4] =
                    make_uint2(h01, h23);
            }
            lsum[ih] += ls;
        }
        // P (A-frags) back from wave-private LDS; Z += P * V^T
        bf16x8 pa[2][2];
        #pragma unroll
        for (int ih = 0; ih < 2; ++ih) {
            pa[ih][0] = *(const bf16x8*)&Pme[(ih * 16 + ln) * LDP + q * 8];
            pa[ih][1] = *(const bf16x8*)&Pme[(ih * 16 + ln) * LDP + 32 + q * 8];
        }
        #pragma unroll
        for (int dt = 0; dt < 4; ++dt)
            #pragma unroll
            for (int ih = 0; ih < 2; ++ih) {
                Of[ih][dt] = __builtin_amdgcn_mfma_f32_16x16x32_bf16(pa[ih][0], vb[dt][0], Of[ih][dt], 0, 0, 0);
                Of[ih][dt] = __builtin_amdgcn_mfma_f32_16x16x32_bf16(pa[ih][1], vb[dt][1], Of[ih][dt], 0, 0, 0);
            }
    }
    // normalize and store via LDS transpose (wave-coherent, no barrier)
    float linv_r[2][4];
    #pragma unroll
    for (int ih = 0; ih < 2; ++ih) {
        float l = lsum[ih];
        l += __shfl_xor(l, 16);
        l += __shfl_xor(l, 32);
        float linv = 1.f / l;
        #pragma unroll
        for (int r = 0; r < 4; ++r) linv_r[ih][r] = __shfl(linv, q * 4 + r);
    }
    #pragma unroll
    for (int ih = 0; ih < 2; ++ih)
        #pragma unroll
        for (int dt = 0; dt < 4; ++dt)
            #pragma unroll
            for (int r = 0; r < 4; ++r)
                Pme[(ih * 16 + q * 4 + r) * LDP + dt * 16 + ln] =
                    f2b(Of[ih][dt][r] * linv_r[ih][r]);
    int row = lane >> 1, half = lane & 1;
    size_t zoff = (size_t)(itile * 32 + row) * DIM + half * 32;
    #pragma unroll
    for (int c4 = 0; c4 < 4; ++c4)
        *(float4*)&Zp[zoff + c4 * 8] =
            *(const float4*)&Pme[row * LDP + half * 32 + c4 * 8];
}

// ---------------- Kernel 3: out = Z @ Wo (MFMA, fp32 out) ------------------
// M=8192, N=64, K=768. 256 one-wave blocks; 2 m-tiles per wave for ILP.
__global__ __launch_bounds__(64) void out_kernel(
    const ushort* __restrict__ Z, const ushort* __restrict__ Wot,
    float* __restrict__ out)
{
    int m0 = blockIdx.x * 32;
    int lane = threadIdx.x;
    int ln = lane & 15, q = lane >> 4;
    f32x4 acc[2][4];
    #pragma unroll
    for (int u = 0; u < 2; ++u)
        #pragma unroll
        for (int nt = 0; nt < 4; ++nt) acc[u][nt] = (f32x4){0.f, 0.f, 0.f, 0.f};
    for (int kc = 0; kc < 24; ++kc) {
        bf16x8 a0 = *(const bf16x8*)&Z[(size_t)(m0 + ln) * HD + kc * 32 + q * 8];
        bf16x8 a1 = *(const bf16x8*)&Z[(size_t)(m0 + 16 + ln) * HD + kc * 32 + q * 8];
        #pragma unroll
        for (int nt = 0; nt < 4; ++nt) {
            bf16x8 bf = *(const bf16x8*)&Wot[(size_t)(nt * 16 + ln) * HD + kc * 32 + q * 8];
            acc[0][nt] = __builtin_amdgcn_mfma_f32_16x16x32_bf16(a0, bf, acc[0][nt], 0, 0, 0);
            acc[1][nt] = __builtin_amdgcn_mfma_f32_16x16x32_bf16(a1, bf, acc[1][nt], 0, 0, 0);
        }
    }
    #pragma unroll
    for (int u = 0; u < 2; ++u)
        #pragma unroll
        for (int nt = 0; nt < 4; ++nt)
            #pragma unroll
            for (int r = 0; r < 4; ++r)
                out[(size_t)(m0 + u * 16 + q * 4 + r) * DIM + nt * 16 + ln] = acc[u][nt][r];
}

extern "C" void kernel_launch(void* const* d_in, const int* in_sizes, int n_in,
                              void* d_out, int out_size, void* d_ws, size_t ws_size,
                              hipStream_t stream)
{
    const float* x  = (const float*)d_in[0];
    const float* Wq = (const float*)d_in[1];
    const float* Wk = (const float*)d_in[2];
    const float* Wv = (const float*)d_in[3];
    const float* Wo = (const float*)d_in[4];
    float* out = (float*)d_out;

    const size_t n = (size_t)BT * HD;            // 6,291,456
    ushort* Q   = (ushort*)d_ws;
    ushort* K   = Q + n;
    ushort* V   = K + n;                         // Z aliases V (V dead after vtrans)
    ushort* Vt  = V + n;
    ushort* xb  = Vt;                            // xb/Wt live only until qkv;
    ushort* Wt  = Vt + (size_t)BT * DIM;         //   overwritten by vtrans's Vt
    ushort* Wot = Vt + n;                        // +96KB tail, lives to the end
    ushort* Z   = V;

    prep_kernel<<<304, 256, 0, stream>>>(x, Wq, Wk, Wv, Wo, xb, Wt, Wot);
    qkv_kernel<<<dim3(128, 36), 256, 0, stream>>>(xb, Wt, Q, K, V);
    vtrans_kernel<<<dim3(32, 48), 256, 0, stream>>>(V, Vt);
    attn_kernel<<<3072, 64, 0, stream>>>(Q, K, Vt, Z);
    out_kernel<<<256, 64, 0, stream>>>(Z, Wot, out);
}

// Round 7
// 180.491 us; speedup vs baseline: 1.7216x; 1.7216x over previous
//
#include <hip/hip_runtime.h>
#include <hip/hip_bf16.h>

// MultiHeadAttention: B=4, T=2048, DIM=64, H=12. fp32 I/O.
// Flat-reshape semantics: QKV are (8192,768) row-major; attention slices are
// contiguous 131072-elem chunks. Roles: queries = K rows (i), keys = Q rows
// (j), values = V rows, softmax over j.
// Round 7: round-5 attn structure (LDS staging + barriers, 256-thr blocks)
// + register-prefetch double-buffer (load latency hidden behind compute)
// + Q pre-scaled by 0.125*log2e at qkv (p = exp2(S) directly)
// + truncation-packed P. qkv reads fp32 x directly (prep_x deleted).

#define DIM 64
#define NH 12
#define HD 768
#define BT 8192
#define TSEQ 2048
#define NSLICE 48
#define SLICE (TSEQ*DIM)

#define LDQ 72   // LDS row strides (ushorts): 16B-aligned rows, 2-way banks
#define LDP 72
#define LDT 72

typedef unsigned short ushort;
typedef __attribute__((ext_vector_type(8))) short bf16x8;
typedef __attribute__((ext_vector_type(4))) float f32x4;

#define SCALE2 0.18033688011112042f   // 0.125 * log2(e)

__device__ __forceinline__ ushort f2b(float f) {
    union { float f; unsigned int i; } v; v.f = f;
    unsigned int x = v.i;
    return (ushort)((x + 0x7fffu + ((x >> 16) & 1u)) >> 16);  // RNE
}

// ---------------- prep: transpose + convert weights ------------------------
// 48 blocks: z = bx/12 (Wq,Wk,Wv,Wo), tile = bx%12.
__global__ __launch_bounds__(256) void prep_w(
    const float* __restrict__ Wq, const float* __restrict__ Wk,
    const float* __restrict__ Wv, const float* __restrict__ Wo,
    ushort* __restrict__ Wt, ushort* __restrict__ Wot)
{
    __shared__ float tile[64][65];
    int bx = blockIdx.x;
    int z = bx / 12, bt = bx % 12;
    const float* __restrict__ IN = (z == 0) ? Wq : (z == 1) ? Wk : (z == 2) ? Wv : Wo;
    int inStride  = (z < 3) ? HD : DIM;
    int outStride = (z < 3) ? DIM : HD;
    int rbase = (z < 3) ? 0 : bt * 64;
    int cbase = (z < 3) ? bt * 64 : 0;
    ushort* __restrict__ OUT = (z < 3) ? (Wt + (size_t)z * HD * DIM) : Wot;
    int t = threadIdx.x;
    int r = t >> 2, c0 = (t & 3) * 16;
    #pragma unroll
    for (int cc = 0; cc < 16; cc += 4) {
        float4 a = *(const float4*)&IN[(size_t)(rbase + r) * inStride + cbase + c0 + cc];
        tile[r][c0 + cc] = a.x; tile[r][c0 + cc + 1] = a.y;
        tile[r][c0 + cc + 2] = a.z; tile[r][c0 + cc + 3] = a.w;
    }
    __syncthreads();
    int cl = t >> 2, r0 = (t & 3) * 16;
    ushort tmp[16] __attribute__((aligned(16)));
    #pragma unroll
    for (int rr = 0; rr < 16; ++rr) tmp[rr] = f2b(tile[r0 + rr][cl]);
    *(float4*)&OUT[(size_t)(cbase + cl) * outStride + rbase + r0] = *(const float4*)tmp;
    *(float4*)&OUT[(size_t)(cbase + cl) * outStride + rbase + r0 + 8] = *(const float4*)&tmp[8];
}

// ---------------- Kernel 1: Q/K/V = x @ W (MFMA; x read as fp32) -----------
// grid (128 row-tiles, 2 halves), 256 thr = 4 waves; wave owns 16 rows and
// loops 18 col-tiles. Q written pre-scaled by SCALE2.
__global__ __launch_bounds__(256) void qkv_kernel(
    const float* __restrict__ x, const ushort* __restrict__ Wt,
    ushort* __restrict__ Q, ushort* __restrict__ K, ushort* __restrict__ V)
{
    int rt = blockIdx.x, half = blockIdx.y;
    int t = threadIdx.x, w = t >> 6, lane = t & 63;
    int ln = lane & 15, q = lane >> 4;
    int m0 = rt * 64 + w * 16;

    // A-frags from fp32 x, converted in-reg (once per wave)
    float4 xa = *(const float4*)&x[(size_t)(m0 + ln) * DIM + q * 8];
    float4 xb_ = *(const float4*)&x[(size_t)(m0 + ln) * DIM + q * 8 + 4];
    float4 xc = *(const float4*)&x[(size_t)(m0 + ln) * DIM + 32 + q * 8];
    float4 xd = *(const float4*)&x[(size_t)(m0 + ln) * DIM + 32 + q * 8 + 4];
    ushort ta[8] __attribute__((aligned(16)));
    ushort tb[8] __attribute__((aligned(16)));
    ta[0]=f2b(xa.x); ta[1]=f2b(xa.y); ta[2]=f2b(xa.z); ta[3]=f2b(xa.w);
    ta[4]=f2b(xb_.x); ta[5]=f2b(xb_.y); ta[6]=f2b(xb_.z); ta[7]=f2b(xb_.w);
    tb[0]=f2b(xc.x); tb[1]=f2b(xc.y); tb[2]=f2b(xc.z); tb[3]=f2b(xc.w);
    tb[4]=f2b(xd.x); tb[5]=f2b(xd.y); tb[6]=f2b(xd.z); tb[7]=f2b(xd.w);
    bf16x8 af0 = *(const bf16x8*)ta;
    bf16x8 af1 = *(const bf16x8*)tb;

    for (int cc = 0; cc < 18; ++cc) {
        int ct = half * 18 + cc;
        int which = ct / 12;
        int col0 = (ct % 12) * 64;
        const ushort* __restrict__ Wz = Wt + (size_t)which * HD * DIM;  // (768x64)
        ushort* __restrict__ Y = (which == 0) ? Q : (which == 1) ? K : V;
        float sc = (which == 0) ? SCALE2 : 1.f;
        #pragma unroll
        for (int nt = 0; nt < 4; ++nt) {
            int n = col0 + nt * 16 + ln;
            bf16x8 bf0 = *(const bf16x8*)&Wz[(size_t)n * DIM + q * 8];
            bf16x8 bf1 = *(const bf16x8*)&Wz[(size_t)n * DIM + 32 + q * 8];
            f32x4 acc = (f32x4){0.f, 0.f, 0.f, 0.f};
            acc = __builtin_amdgcn_mfma_f32_16x16x32_bf16(af0, bf0, acc, 0, 0, 0);
            acc = __builtin_amdgcn_mfma_f32_16x16x32_bf16(af1, bf1, acc, 0, 0, 0);
            #pragma unroll
            for (int r = 0; r < 4; ++r)
                Y[(size_t)(m0 + q * 4 + r) * HD + col0 + nt * 16 + ln] = f2b(acc[r] * sc);
        }
    }
}

// ---------------- Kernel 1b: Vt[s][d][t] = V[s][t][d] ----------------------
// XOR-swizzled transposed scalar writes (banks spread), vector reads un-swizzle.
__global__ __launch_bounds__(256) void vtrans_kernel(
    const ushort* __restrict__ V, ushort* __restrict__ Vt)
{
    __shared__ ushort tileT[64 * LDT];
    int tt = blockIdx.x, s = blockIdx.y;
    const ushort* __restrict__ Vp = V + (size_t)s * SLICE;
    ushort* __restrict__ Vo = Vt + (size_t)s * SLICE;
    int t = threadIdx.x;
    int r = t >> 3, c = (t & 7) * 8;
    ushort va[8] __attribute__((aligned(16)));
    ushort vb[8] __attribute__((aligned(16)));
    *(float4*)va = *(const float4*)&Vp[(size_t)(tt * 64 + r) * DIM + c];
    *(float4*)vb = *(const float4*)&Vp[(size_t)(tt * 64 + r + 32) * DIM + c];
    int g0 = ((r >> 3) ^ (c >> 3)) * 8 + (r & 7);
    int g1 = (((r + 32) >> 3) ^ (c >> 3)) * 8 + (r & 7);
    #pragma unroll
    for (int k = 0; k < 8; ++k) {
        tileT[(c + k) * LDT + g0] = va[k];
        tileT[(c + k) * LDT + g1] = vb[k];
    }
    __syncthreads();
    #pragma unroll
    for (int j = 0; j < 2; ++j) {
        int flat = t + 256 * j;
        int d = flat >> 3, tg = flat & 7;
        int sg = tg ^ ((d >> 3) & 7);
        float4 vv = *(const float4*)&tileT[d * LDT + sg * 8];
        *(float4*)&Vo[(size_t)d * TSEQ + tt * 64 + tg * 8] = vv;
    }
}

// ---------------- Kernel 2: MFMA flash attention (reg-prefetch dbuf) -------
// grid (16 i-tiles, 48 slices), 256 thr = 4 waves; wave owns 32 i-rows.
// Next tile's Q/V loads issue right after the LDS-ready barrier into VGPRs;
// only 4 ds_write_b128 sit between the barrier pair.
__global__ __launch_bounds__(256) void attn_kernel(
    const ushort* __restrict__ Qs, const ushort* __restrict__ Ks,
    const ushort* __restrict__ Vts, ushort* __restrict__ Zs)
{
    __shared__ ushort Qt[64 * LDQ];
    __shared__ ushort Vtile[64 * LDQ];
    __shared__ ushort Pw[128 * LDP];
    int itile = blockIdx.x, s = blockIdx.y;
    const ushort* __restrict__ Qp = Qs + (size_t)s * SLICE;
    const ushort* __restrict__ Kp = Ks + (size_t)s * SLICE;
    const ushort* __restrict__ Vp = Vts + (size_t)s * SLICE;   // [64][2048]
    ushort* __restrict__ Zp = Zs + (size_t)s * SLICE;
    int t = threadIdx.x, w = t >> 6, lane = t & 63;
    int ln = lane & 15, q = lane >> 4;

    bf16x8 kf[2][2];
    #pragma unroll
    for (int ih = 0; ih < 2; ++ih) {
        int i0 = itile * 128 + w * 32 + ih * 16 + ln;
        kf[ih][0] = *(const bf16x8*)&Kp[(size_t)i0 * DIM + q * 8];
        kf[ih][1] = *(const bf16x8*)&Kp[(size_t)i0 * DIM + 32 + q * 8];
    }
    f32x4 Of[2][4];
    #pragma unroll
    for (int ih = 0; ih < 2; ++ih)
        #pragma unroll
        for (int dt = 0; dt < 4; ++dt) Of[ih][dt] = (f32x4){0.f, 0.f, 0.f, 0.f};
    float lsum[2] = {0.f, 0.f};
    ushort* Pme = &Pw[w * 32 * LDP];

    int sr = t >> 3, sc = (t & 7) * 8;
    // prefetch tile 0
    float4 qa0 = *(const float4*)&Qp[(size_t)sr * DIM + sc];
    float4 qa1 = *(const float4*)&Qp[(size_t)(sr + 32) * DIM + sc];
    float4 va0 = *(const float4*)&Vp[(size_t)sr * TSEQ + sc];
    float4 va1 = *(const float4*)&Vp[(size_t)(sr + 32) * TSEQ + sc];

    for (int jt = 0; jt < TSEQ; jt += 64) {
        __syncthreads();                       // consumers of prev tile done
        *(float4*)&Qt[sr * LDQ + sc] = qa0;
        *(float4*)&Qt[(sr + 32) * LDQ + sc] = qa1;
        *(float4*)&Vtile[sr * LDQ + sc] = va0;
        *(float4*)&Vtile[(sr + 32) * LDQ + sc] = va1;
        __syncthreads();                       // tile ready
        if (jt + 64 < TSEQ) {                  // prefetch next tile into regs
            qa0 = *(const float4*)&Qp[(size_t)(jt + 64 + sr) * DIM + sc];
            qa1 = *(const float4*)&Qp[(size_t)(jt + 64 + sr + 32) * DIM + sc];
            va0 = *(const float4*)&Vp[(size_t)sr * TSEQ + jt + 64 + sc];
            va1 = *(const float4*)&Vp[(size_t)(sr + 32) * TSEQ + jt + 64 + sc];
        }

        // S^T = Q*K^T (Q pre-scaled: S is already in log2-units)
        f32x4 Sf[2][4];
        #pragma unroll
        for (int mt = 0; mt < 4; ++mt) {
            bf16x8 a0 = *(const bf16x8*)&Qt[(mt * 16 + ln) * LDQ + q * 8];
            bf16x8 a1 = *(const bf16x8*)&Qt[(mt * 16 + ln) * LDQ + 32 + q * 8];
            #pragma unroll
            for (int ih = 0; ih < 2; ++ih) {
                f32x4 acc = (f32x4){0.f, 0.f, 0.f, 0.f};
                acc = __builtin_amdgcn_mfma_f32_16x16x32_bf16(a0, kf[ih][0], acc, 0, 0, 0);
                acc = __builtin_amdgcn_mfma_f32_16x16x32_bf16(a1, kf[ih][1], acc, 0, 0, 0);
                Sf[ih][mt] = acc;
            }
        }
        // p = exp2(S); truncation-pack into wave-private LDS; l from truncated
        #pragma unroll
        for (int ih = 0; ih < 2; ++ih) {
            float ls = 0.f;
            #pragma unroll
            for (int mt = 0; mt < 4; ++mt) {
                float p0 = __builtin_amdgcn_exp2f(Sf[ih][mt][0]);
                float p1 = __builtin_amdgcn_exp2f(Sf[ih][mt][1]);
                float p2 = __builtin_amdgcn_exp2f(Sf[ih][mt][2]);
                float p3 = __builtin_amdgcn_exp2f(Sf[ih][mt][3]);
                unsigned int b0 = __float_as_uint(p0), b1 = __float_as_uint(p1);
                unsigned int b2 = __float_as_uint(p2), b3 = __float_as_uint(p3);
                unsigned int t1 = b1 & 0xFFFF0000u, t3 = b3 & 0xFFFF0000u;
                unsigned int h01 = (b0 >> 16) | t1;
                unsigned int h23 = (b2 >> 16) | t3;
                ls += __uint_as_float(h01 << 16) + __uint_as_float(t1)
                    + __uint_as_float(h23 << 16) + __uint_as_float(t3);
                *(uint2*)&Pme[(ih * 16 + ln) * LDP + mt * 16 + q * 4] =
                    make_uint2(h01, h23);
            }
            lsum[ih] += ls;
        }
        // Z += P * V^T (wave-private P: no barrier)
        bf16x8 pa[2][2];
        #pragma unroll
        for (int ih = 0; ih < 2; ++ih) {
            pa[ih][0] = *(const bf16x8*)&Pme[(ih * 16 + ln) * LDP + q * 8];
            pa[ih][1] = *(const bf16x8*)&Pme[(ih * 16 + ln) * LDP + 32 + q * 8];
        }
        #pragma unroll
        for (int dt = 0; dt < 4; ++dt) {
            bf16x8 vb0 = *(const bf16x8*)&Vtile[(dt * 16 + ln) * LDQ + q * 8];
            bf16x8 vb1 = *(const bf16x8*)&Vtile[(dt * 16 + ln) * LDQ + 32 + q * 8];
            #pragma unroll
            for (int ih = 0; ih < 2; ++ih) {
                Of[ih][dt] = __builtin_amdgcn_mfma_f32_16x16x32_bf16(pa[ih][0], vb0, Of[ih][dt], 0, 0, 0);
                Of[ih][dt] = __builtin_amdgcn_mfma_f32_16x16x32_bf16(pa[ih][1], vb1, Of[ih][dt], 0, 0, 0);
            }
        }
    }
    // final l reduction, normalize, store via LDS for coalesced writes
    float linv_r[2][4];
    #pragma unroll
    for (int ih = 0; ih < 2; ++ih) {
        float l = lsum[ih];
        l += __shfl_xor(l, 16);
        l += __shfl_xor(l, 32);
        float linv = 1.f / l;
        #pragma unroll
        for (int r = 0; r < 4; ++r) linv_r[ih][r] = __shfl(linv, q * 4 + r);
    }
    #pragma unroll
    for (int ih = 0; ih < 2; ++ih)
        #pragma unroll
        for (int dt = 0; dt < 4; ++dt)
            #pragma unroll
            for (int r = 0; r < 4; ++r)
                Pme[(ih * 16 + q * 4 + r) * LDP + dt * 16 + ln] =
                    f2b(Of[ih][dt][r] * linv_r[ih][r]);
    __syncthreads();
    int zr = t >> 1, zc = (t & 1) * 32;
    size_t zoff = (size_t)(itile * 128 + zr) * DIM + zc;
    #pragma unroll
    for (int c4 = 0; c4 < 4; ++c4)
        *(float4*)&Zp[zoff + c4 * 8] = *(const float4*)&Pw[zr * LDP + zc + c4 * 8];
}

// ---------------- Kernel 3: out = Z @ Wo (MFMA, fp32 out) ------------------
// M=8192, N=64, K=768. 256 one-wave blocks; 2 m-tiles per wave for ILP.
__global__ __launch_bounds__(64) void out_kernel(
    const ushort* __restrict__ Z, const ushort* __restrict__ Wot,
    float* __restrict__ out)
{
    int m0 = blockIdx.x * 32;
    int lane = threadIdx.x;
    int ln = lane & 15, q = lane >> 4;
    f32x4 acc[2][4];
    #pragma unroll
    for (int u = 0; u < 2; ++u)
        #pragma unroll
        for (int nt = 0; nt < 4; ++nt) acc[u][nt] = (f32x4){0.f, 0.f, 0.f, 0.f};
    for (int kc = 0; kc < 24; ++kc) {
        bf16x8 a0 = *(const bf16x8*)&Z[(size_t)(m0 + ln) * HD + kc * 32 + q * 8];
        bf16x8 a1 = *(const bf16x8*)&Z[(size_t)(m0 + 16 + ln) * HD + kc * 32 + q * 8];
        #pragma unroll
        for (int nt = 0; nt < 4; ++nt) {
            bf16x8 bf = *(const bf16x8*)&Wot[(size_t)(nt * 16 + ln) * HD + kc * 32 + q * 8];
            acc[0][nt] = __builtin_amdgcn_mfma_f32_16x16x32_bf16(a0, bf, acc[0][nt], 0, 0, 0);
            acc[1][nt] = __builtin_amdgcn_mfma_f32_16x16x32_bf16(a1, bf, acc[1][nt], 0, 0, 0);
        }
    }
    #pragma unroll
    for (int u = 0; u < 2; ++u)
        #pragma unroll
        for (int nt = 0; nt < 4; ++nt)
            #pragma unroll
            for (int r = 0; r < 4; ++r)
                out[(size_t)(m0 + u * 16 + q * 4 + r) * DIM + nt * 16 + ln] = acc[u][nt][r];
}

extern "C" void kernel_launch(void* const* d_in, const int* in_sizes, int n_in,
                              void* d_out, int out_size, void* d_ws, size_t ws_size,
                              hipStream_t stream)
{
    const float* x  = (const float*)d_in[0];
    const float* Wq = (const float*)d_in[1];
    const float* Wk = (const float*)d_in[2];
    const float* Wv = (const float*)d_in[3];
    const float* Wo = (const float*)d_in[4];
    float* out = (float*)d_out;

    const size_t n = (size_t)BT * HD;            // 6,291,456
    ushort* Q   = (ushort*)d_ws;
    ushort* K   = Q + n;
    ushort* V   = K + n;                         // Z aliases V (V dead after vtrans)
    ushort* Vt  = V + n;
    ushort* Wt  = Vt;                            // Wt lives only until qkv done;
    ushort* Wot = Vt + n;                        //   then vtrans overwrites with Vt
    ushort* Z   = V;

    prep_w<<<48, 256, 0, stream>>>(Wq, Wk, Wv, Wo, Wt, Wot);
    qkv_kernel<<<dim3(128, 2), 256, 0, stream>>>(x, Wt, Q, K, V);
    vtrans_kernel<<<dim3(32, 48), 256, 0, stream>>>(V, Vt);
    attn_kernel<<<dim3(16, 48), 256, 0, stream>>>(Q, K, Vt, Z);
    out_kernel<<<256, 64, 0, stream>>>(Z, Wot, out);
}